// Round 5
// baseline (113.011 us; speedup 1.0000x reference)
//
#include <hip/hip_runtime.h>
#include <hip/hip_bf16.h>

#define NN  512
#define CC  64
#define HID 256
#define H4  (HID/4)
#define PSTRIDE (NN*HID)
#define PROWS 4                  // 4 rows/block: halves W1 L2 re-read traffic

typedef short  bf16x8 __attribute__((ext_vector_type(8)));
typedef float  f32x4  __attribute__((ext_vector_type(4)));

__device__ __forceinline__ short b16(float x) {
  __hip_bfloat16 t = __float2bfloat16(x);
  return *(short*)&t;
}

__device__ __forceinline__ float celu1(float x) {
  float e = __expf(x) - 1.f;
  return x > 0.f ? x : e;
}

// ---------------------------------------------------------------------------
// Kernel 1: 6 small projections. P slots: [PA,PC,PE,PB,PD,PF], b1 in PA.
// ---------------------------------------------------------------------------
__global__ __launch_bounds__(256) void proj_kernel(
    const float* __restrict__ xl, const float* __restrict__ xr,
    const float* __restrict__ W1, const float* __restrict__ b1,
    float* __restrict__ P)
{
  const int side = blockIdx.y;
  const int i0   = blockIdx.x * PROWS;
  const int h    = threadIdx.x;
  const float* __restrict__ x = side ? xr : xl;

  __shared__ float xs[PROWS][CC];
  // PROWS*CC == 256 == blockDim.x
  xs[threadIdx.x >> 6][threadIdx.x & 63] = x[i0 * CC + threadIdx.x];
  __syncthreads();

  float acc0[PROWS], acc1[PROWS], acc2[PROWS];
#pragma unroll
  for (int r = 0; r < PROWS; r++) { acc0[r] = 0.f; acc1[r] = 0.f; acc2[r] = 0.f; }

  const int base = side ? CC : 0;
  const float* __restrict__ w0p = W1 + (base      ) * HID + h;
  const float* __restrict__ w1p = W1 + (base + 128) * HID + h;
  const float* __restrict__ w2p = W1 + (base + 256) * HID + h;
#pragma unroll 8
  for (int c = 0; c < CC; c++) {
    float w0 = w0p[c * HID];
    float w1 = w1p[c * HID];
    float w2 = w2p[c * HID];
#pragma unroll
    for (int r = 0; r < PROWS; r++) {
      float xv = xs[r][c];
      acc0[r] = fmaf(xv, w0, acc0[r]);
      acc1[r] = fmaf(xv, w1, acc1[r]);
      acc2[r] = fmaf(xv, w2, acc2[r]);
    }
  }

  float* __restrict__ O0 = P + (side ? 3 : 0) * PSTRIDE;
  float* __restrict__ O1 = P + (side ? 4 : 1) * PSTRIDE;
  float* __restrict__ O2 = P + (side ? 5 : 2) * PSTRIDE;
  const float bb = side ? 0.f : b1[h];
#pragma unroll
  for (int r = 0; r < PROWS; r++) {
    O0[(i0 + r) * HID + h] = acc0[r] + bb;
    O1[(i0 + r) * HID + h] = acc1[r];
    O2[(i0 + r) * HID + h] = acc2[r];
  }
}

// ---------------------------------------------------------------------------
// Kernel 2 (merged): three independent roles in one launch — all read only P
// (proj output), so no intra-kernel ordering is needed:
//   blocks [0,512):    prep rows — U/V f32, Vt transpose, rowstat sums.
//   blocks [512,768):  cross tiles — self-compute bf16 U/V fragments from P
//                      (same expression + same __float2bfloat16 rounding as
//                      prep -> Cross bit-identical to the old 2-kernel path).
//   blocks [768,1024): border pairs (2044), 2 pairs per wave, direct from P.
// Replaces prep + cross + (border part of pair): 4 launches -> 3, roles
// overlap instead of serializing. Ubf/Vbf buffers eliminated.
// ---------------------------------------------------------------------------
__global__ __launch_bounds__(256) void mid_kernel(
    const float* __restrict__ P,
    float* __restrict__ Uf, float* __restrict__ Vt,
    float* __restrict__ rowstat, float* __restrict__ Cross,
    const float* __restrict__ gamma, const float* __restrict__ beta,
    const float* __restrict__ W2, const float* __restrict__ b2,
    float* __restrict__ out)
{
  const int wave = threadIdx.x >> 6, lane = threadIdx.x & 63;

  if (blockIdx.x < 512) {
    // ---- prep role -------------------------------------------------------
    const int r = blockIdx.x, h = threadIdx.x;
    const float* __restrict__ PA = P;
    const float* __restrict__ PC = P + 1 * PSTRIDE;
    const float* __restrict__ PE = P + 2 * PSTRIDE;
    const float* __restrict__ PB = P + 3 * PSTRIDE;
    const float* __restrict__ PD = P + 4 * PSTRIDE;
    const float* __restrict__ PF = P + 5 * PSTRIDE;

    float u = PA[r * HID + h] + PC[(r - 1) * HID + h] + PE[(r + 1) * HID + h];
    float v = PB[r * HID + h] + PD[(r + 1) * HID + h] + PF[(r - 1) * HID + h];
    Uf[r * HID + h] = u;
    Vt[((h >> 2) * NN + r) * 4 + (h & 3)] = v;

    float u2 = u * u, v2 = v * v;
#pragma unroll
    for (int k = 32; k >= 1; k >>= 1) {
      u  += __shfl_xor(u,  k, 64);
      u2 += __shfl_xor(u2, k, 64);
      v  += __shfl_xor(v,  k, 64);
      v2 += __shfl_xor(v2, k, 64);
    }
    __shared__ float red[4][4];
    const int w = h >> 6;
    if ((h & 63) == 0) { red[w][0] = u; red[w][1] = u2; red[w][2] = v; red[w][3] = v2; }
    __syncthreads();
    if (h < 4)
      rowstat[h * NN + r] = red[0][h] + red[1][h] + red[2][h] + red[3][h];

  } else if (blockIdx.x < 768) {
    // ---- cross role: Cross[i,j] = sum_h U[i,h]*V[j,h], MFMA 16x16x32 -----
    const int t  = (blockIdx.x - 512) * 4 + wave;   // 0..1023
    const int ti = t >> 5, tj = t & 31;
    const int i0 = ti * 16, j0 = tj * 16;
    const int rc = lane & 15, kb = (lane >> 4) * 8;
    const int ri = i0 + rc, rj = j0 + rc;

    const float4* __restrict__ PA4 = (const float4*)(P + 0 * PSTRIDE);
    const float4* __restrict__ PC4 = (const float4*)(P + 1 * PSTRIDE);
    const float4* __restrict__ PE4 = (const float4*)(P + 2 * PSTRIDE);
    const float4* __restrict__ PB4 = (const float4*)(P + 3 * PSTRIDE);
    const float4* __restrict__ PD4 = (const float4*)(P + 4 * PSTRIDE);
    const float4* __restrict__ PF4 = (const float4*)(P + 5 * PSTRIDE);

    f32x4 acc = {0.f, 0.f, 0.f, 0.f};
#pragma unroll
    for (int k = 0; k < HID; k += 32) {
      const int hu = (ri * HID + k + kb) >> 2;          // float4 index, U row
      const int hc = ((ri - 1) * HID + k + kb) >> 2;
      const int he = ((ri + 1) * HID + k + kb) >> 2;
      const float4 a0 = PA4[hu],     a1 = PA4[hu + 1];
      const float4 c0 = PC4[hc],     c1 = PC4[hc + 1];
      const float4 e0 = PE4[he],     e1 = PE4[he + 1];

      const int hv = (rj * HID + k + kb) >> 2;          // float4 index, V row
      const int hd = ((rj + 1) * HID + k + kb) >> 2;
      const int hf = ((rj - 1) * HID + k + kb) >> 2;
      const float4 b0 = PB4[hv],     b1v = PB4[hv + 1];
      const float4 d0 = PD4[hd],     d1 = PD4[hd + 1];
      const float4 f0 = PF4[hf],     f1 = PF4[hf + 1];

      bf16x8 ua, vb;
      ua[0] = b16(a0.x + c0.x + e0.x);
      ua[1] = b16(a0.y + c0.y + e0.y);
      ua[2] = b16(a0.z + c0.z + e0.z);
      ua[3] = b16(a0.w + c0.w + e0.w);
      ua[4] = b16(a1.x + c1.x + e1.x);
      ua[5] = b16(a1.y + c1.y + e1.y);
      ua[6] = b16(a1.z + c1.z + e1.z);
      ua[7] = b16(a1.w + c1.w + e1.w);
      vb[0] = b16(b0.x + d0.x + f0.x);
      vb[1] = b16(b0.y + d0.y + f0.y);
      vb[2] = b16(b0.z + d0.z + f0.z);
      vb[3] = b16(b0.w + d0.w + f0.w);
      vb[4] = b16(b1v.x + d1.x + f1.x);
      vb[5] = b16(b1v.y + d1.y + f1.y);
      vb[6] = b16(b1v.z + d1.z + f1.z);
      vb[7] = b16(b1v.w + d1.w + f1.w);

      acc = __builtin_amdgcn_mfma_f32_16x16x32_bf16(ua, vb, acc, 0, 0, 0);
    }
    const int orow = (lane >> 4) * 4, ocol = lane & 15;
#pragma unroll
    for (int r = 0; r < 4; r++)
      Cross[(size_t)(i0 + orow + r) * NN + j0 + ocol] = acc[r];

  } else {
    // ---- border role: 2044 pairs, 2 per wave -----------------------------
    const int gw = (blockIdx.x - 768) * 4 + wave;      // 0..1023
    const float b2s = b2[0];
    const float4* P4 = (const float4*)P;
    const float4* PA = P4 + 0 * (PSTRIDE / 4);
    const float4* PC = P4 + 1 * (PSTRIDE / 4);
    const float4* PE = P4 + 2 * (PSTRIDE / 4);
    const float4* PB = P4 + 3 * (PSTRIDE / 4);
    const float4* PD = P4 + 4 * (PSTRIDE / 4);
    const float4* PF = P4 + 5 * (PSTRIDE / 4);
    const float4 g  = ((const float4*)gamma)[lane];
    const float4 be = ((const float4*)beta)[lane];
    const float4 w2 = ((const float4*)W2)[lane];

#pragma unroll
    for (int tt = 0; tt < 2; tt++) {
      const int p = gw * 2 + tt;
      if (p >= 2044) break;
      int i, j;
      if      (p < 512)  { i = 0;        j = p;        }
      else if (p < 1024) { i = 511;      j = p - 512;  }
      else if (p < 1534) { i = p - 1023; j = 0;        }
      else               { i = p - 1533; j = 511;      }

      const float4 a  = PA[i * H4 + lane];
      const float4 cu = PC[(i - 1) * H4 + lane];
      const float4 ed = PE[(i + 1) * H4 + lane];
      const float4 b  = PB[j * H4 + lane];
      const float4 du = PD[(j + 1) * H4 + lane];
      const float4 fd = PF[(j - 1) * H4 + lane];
      const float mu_m = (i >= 1 && j <= NN - 2) ? 1.f : 0.f;
      const float md_m = (i <= NN - 2 && j >= 1) ? 1.f : 0.f;

      float s0 = fmaf(md_m, ed.x + fd.x, fmaf(mu_m, cu.x + du.x, a.x + b.x));
      float s1 = fmaf(md_m, ed.y + fd.y, fmaf(mu_m, cu.y + du.y, a.y + b.y));
      float s2 = fmaf(md_m, ed.z + fd.z, fmaf(mu_m, cu.z + du.z, a.z + b.z));
      float s3 = fmaf(md_m, ed.w + fd.w, fmaf(mu_m, cu.w + du.w, a.w + b.w));

      float sum = (s0 + s1) + (s2 + s3);
      float ssq = fmaf(s0, s0, fmaf(s1, s1, fmaf(s2, s2, s3 * s3)));
#pragma unroll
      for (int off = 32; off >= 1; off >>= 1) {
        sum += __shfl_xor(sum, off, 64);
        ssq += __shfl_xor(ssq, off, 64);
      }
      const float mu  = sum * (1.f / HID);
      const float var = fmaf(ssq, 1.f / HID, -mu * mu);
      const float rs  = rsqrtf(var + 1e-5f);
      const float mrs = -mu * rs;

      auto nrm = [&](float s, float G, float Bt) {
        return fmaf(fmaf(s, rs, mrs), G, Bt);
      };
      float racc = fmaf(celu1(nrm(s0, g.x, be.x)), w2.x,
                   fmaf(celu1(nrm(s1, g.y, be.y)), w2.y,
                   fmaf(celu1(nrm(s2, g.z, be.z)), w2.z,
                        celu1(nrm(s3, g.w, be.w)) * w2.w)));
#pragma unroll
      for (int off = 32; off >= 1; off >>= 1)
        racc += __shfl_xor(racc, off, 64);
      if (lane == 0) out[i * NN + j] = racc + b2s;
    }
  }
}

// ---------------------------------------------------------------------------
// Kernel 3: interior pair epilogue (unchanged numerics from R2/R4 winner).
// 2 rows x 256 j per block, 1024 threads = 256 j-slots x 4 h-quarters;
// 510 blocks x 16 waves ~ 2 blocks/CU = 8 waves/SIMD.
// ---------------------------------------------------------------------------
__global__ __launch_bounds__(1024) void pair_kernel(
    const float* __restrict__ Uf, const float* __restrict__ Vt,
    const float* __restrict__ Cross, const float* __restrict__ rowstat,
    const float* __restrict__ gamma, const float* __restrict__ beta,
    const float* __restrict__ W2, const float* __restrict__ b2,
    float* __restrict__ out)
{
  const float b2s = b2[0];

  const int bx = blockIdx.x;                    // 0..509
  const int bi = bx >> 1;                       // 0..254
  const int i0 = 1 + (bi << 1);                 // 1,3,..,509
  const int i1 = i0 + 1;                        // 2,4,..,510
  const int tj = threadIdx.x & 255;             // j slot within half
  const int hq = threadIdx.x >> 8;              // 0..3: h-quarter
  const int jj = ((bx & 1) << 8) + tj;          // 0..511
  const int j  = jj < 1 ? 1 : (jj > 510 ? 510 : jj);

  __shared__ __align__(16) float Gs[HID], Bs[HID], Ws[HID], U0s[HID], U1s[HID];
  __shared__ float part[3][2][256];
  if (threadIdx.x < HID) {
    Gs[threadIdx.x]  = gamma[threadIdx.x];
    Bs[threadIdx.x]  = beta[threadIdx.x];
    Ws[threadIdx.x]  = W2[threadIdx.x];
    U0s[threadIdx.x] = Uf[i0 * HID + threadIdx.x];
    U1s[threadIdx.x] = Uf[i1 * HID + threadIdx.x];
  }
  __syncthreads();

  const float inv = 1.f / HID;
  const float sV  = rowstat[2 * NN + j], sV2 = rowstat[3 * NN + j];

  const float mu0 = (rowstat[0 * NN + i0] + sV) * inv;
  const float tq0 = fmaf(2.f, Cross[i0 * NN + j], rowstat[1 * NN + i0] + sV2) * inv;
  const float rs0 = rsqrtf(tq0 - mu0 * mu0 + 1e-5f);
  const float mr0 = -mu0 * rs0;

  const float mu1 = (rowstat[0 * NN + i1] + sV) * inv;
  const float tq1 = fmaf(2.f, Cross[i1 * NN + j], rowstat[1 * NN + i1] + sV2) * inv;
  const float rs1 = rsqrtf(tq1 - mu1 * mu1 + 1e-5f);
  const float mr1 = -mu1 * rs1;

  float acc0 = 0.f, acc1 = 0.f;
  const float4* __restrict__ Vp  = (const float4*)Vt;   // [hb*NN + j]
  const float4* __restrict__ G4  = (const float4*)Gs;
  const float4* __restrict__ B4  = (const float4*)Bs;
  const float4* __restrict__ W4  = (const float4*)Ws;
  const float4* __restrict__ U04 = (const float4*)U0s;
  const float4* __restrict__ U14 = (const float4*)U1s;

  const int hb0 = hq << 4;                              // 0,16,32,48
#pragma unroll 4
  for (int hb = hb0; hb < hb0 + 16; hb++) {
    const float4 v4  = Vp[hb * NN + j];
    const float4 g   = G4[hb];
    const float4 be4 = B4[hb];
    const float4 w4  = W4[hb];
    const float4 u0  = U04[hb];
    const float4 u1  = U14[hb];
    {
      const float n0 = fmaf(fmaf(v4.x + u0.x, rs0, mr0), g.x, be4.x);
      acc0 = fmaf(celu1(n0), w4.x, acc0);
      const float n1 = fmaf(fmaf(v4.x + u1.x, rs1, mr1), g.x, be4.x);
      acc1 = fmaf(celu1(n1), w4.x, acc1);
    }
    {
      const float n0 = fmaf(fmaf(v4.y + u0.y, rs0, mr0), g.y, be4.y);
      acc0 = fmaf(celu1(n0), w4.y, acc0);
      const float n1 = fmaf(fmaf(v4.y + u1.y, rs1, mr1), g.y, be4.y);
      acc1 = fmaf(celu1(n1), w4.y, acc1);
    }
    {
      const float n0 = fmaf(fmaf(v4.z + u0.z, rs0, mr0), g.z, be4.z);
      acc0 = fmaf(celu1(n0), w4.z, acc0);
      const float n1 = fmaf(fmaf(v4.z + u1.z, rs1, mr1), g.z, be4.z);
      acc1 = fmaf(celu1(n1), w4.z, acc1);
    }
    {
      const float n0 = fmaf(fmaf(v4.w + u0.w, rs0, mr0), g.w, be4.w);
      acc0 = fmaf(celu1(n0), w4.w, acc0);
      const float n1 = fmaf(fmaf(v4.w + u1.w, rs1, mr1), g.w, be4.w);
      acc1 = fmaf(celu1(n1), w4.w, acc1);
    }
  }
  if (hq > 0) { part[hq - 1][0][tj] = acc0; part[hq - 1][1][tj] = acc1; }
  __syncthreads();
  if (hq == 0 && jj >= 1 && jj <= 510) {
    out[i0 * NN + jj] =
        ((acc0 + part[0][0][tj]) + (part[1][0][tj] + part[2][0][tj])) + b2s;
    out[i1 * NN + jj] =
        ((acc1 + part[0][1][tj]) + (part[1][1][tj] + part[2][1][tj])) + b2s;
  }
}

extern "C" void kernel_launch(void* const* d_in, const int* in_sizes, int n_in,
                              void* d_out, int out_size, void* d_ws, size_t ws_size,
                              hipStream_t stream)
{
  const float* xl    = (const float*)d_in[0];
  const float* xr    = (const float*)d_in[1];
  const float* W1    = (const float*)d_in[2];
  const float* b1    = (const float*)d_in[3];
  const float* gamma = (const float*)d_in[4];
  const float* beta  = (const float*)d_in[5];
  const float* W2    = (const float*)d_in[6];
  const float* b2    = (const float*)d_in[7];
  float* out = (float*)d_out;

  float* P       = (float*)d_ws;                     // 3 MB
  float* Uf      = P + 6 * PSTRIDE;                  // 0.5 MB
  float* Vt      = Uf + NN * HID;                    // 0.5 MB (transposed V)
  float* Cross   = Vt + NN * HID;                    // 1 MB
  float* rowstat = Cross + NN * NN;                  // 8 KB

  proj_kernel<<<dim3(NN / PROWS, 2), 256, 0, stream>>>(xl, xr, W1, b1, P);
  mid_kernel<<<1024, 256, 0, stream>>>(P, Uf, Vt, rowstat, Cross,
                                       gamma, beta, W2, b2, out);
  pair_kernel<<<510, 1024, 0, stream>>>(Uf, Vt, Cross, rowstat,
                                        gamma, beta, W2, b2, out);
}

// Round 6
// 104.416 us; speedup vs baseline: 1.0823x; 1.0823x over previous
//
#include <hip/hip_runtime.h>
#include <hip/hip_bf16.h>

#define NN  512
#define CC  64
#define HID 256
#define H4  (HID/4)
#define PSTRIDE (NN*HID)
#define PROWS 4                  // 4 rows/block: halves W1 L2 re-read traffic
#define NB_BORDER 128            // border blocks (16 waves each), dispatched first

typedef float  f32x4  __attribute__((ext_vector_type(4)));

__device__ __forceinline__ float celu1(float x) {
  float e = __expf(x) - 1.f;
  return x > 0.f ? x : e;
}

// ---------------------------------------------------------------------------
// Kernel 1: 6 small projections. P slots: [PA,PC,PE,PB,PD,PF], b1 in PA.
// ---------------------------------------------------------------------------
__global__ __launch_bounds__(256) void proj_kernel(
    const float* __restrict__ xl, const float* __restrict__ xr,
    const float* __restrict__ W1, const float* __restrict__ b1,
    float* __restrict__ P)
{
  const int side = blockIdx.y;
  const int i0   = blockIdx.x * PROWS;
  const int h    = threadIdx.x;
  const float* __restrict__ x = side ? xr : xl;

  __shared__ float xs[PROWS][CC];
  // PROWS*CC == 256 == blockDim.x
  xs[threadIdx.x >> 6][threadIdx.x & 63] = x[i0 * CC + threadIdx.x];
  __syncthreads();

  float acc0[PROWS], acc1[PROWS], acc2[PROWS];
#pragma unroll
  for (int r = 0; r < PROWS; r++) { acc0[r] = 0.f; acc1[r] = 0.f; acc2[r] = 0.f; }

  const int base = side ? CC : 0;
  const float* __restrict__ w0p = W1 + (base      ) * HID + h;
  const float* __restrict__ w1p = W1 + (base + 128) * HID + h;
  const float* __restrict__ w2p = W1 + (base + 256) * HID + h;
#pragma unroll 8
  for (int c = 0; c < CC; c++) {
    float w0 = w0p[c * HID];
    float w1 = w1p[c * HID];
    float w2 = w2p[c * HID];
#pragma unroll
    for (int r = 0; r < PROWS; r++) {
      float xv = xs[r][c];
      acc0[r] = fmaf(xv, w0, acc0[r]);
      acc1[r] = fmaf(xv, w1, acc1[r]);
      acc2[r] = fmaf(xv, w2, acc2[r]);
    }
  }

  float* __restrict__ O0 = P + (side ? 3 : 0) * PSTRIDE;
  float* __restrict__ O1 = P + (side ? 4 : 1) * PSTRIDE;
  float* __restrict__ O2 = P + (side ? 5 : 2) * PSTRIDE;
  const float bb = side ? 0.f : b1[h];
#pragma unroll
  for (int r = 0; r < PROWS; r++) {
    O0[(i0 + r) * HID + h] = acc0[r] + bb;
    O1[(i0 + r) * HID + h] = acc1[r];
    O2[(i0 + r) * HID + h] = acc2[r];
  }
}

// ---------------------------------------------------------------------------
// Kernel 2: prep. U_i = PA[i]+PC[i-1]+PE[i+1], V_j = PB[j]+PD[j+1]+PF[j-1].
// Writes Uf, transposed Vt, rowstat=[sU,sU2,sV,sV2]. (bf16 copies removed —
// the cross GEMM is now fused into pair_kernel as f32 dots.)
// ---------------------------------------------------------------------------
__global__ __launch_bounds__(256) void prep_kernel(
    const float* __restrict__ P,
    float* __restrict__ Uf, float* __restrict__ Vt,
    float* __restrict__ rowstat)
{
  const int r = blockIdx.x, h = threadIdx.x;
  const float* __restrict__ PA = P;
  const float* __restrict__ PC = P + 1 * PSTRIDE;
  const float* __restrict__ PE = P + 2 * PSTRIDE;
  const float* __restrict__ PB = P + 3 * PSTRIDE;
  const float* __restrict__ PD = P + 4 * PSTRIDE;
  const float* __restrict__ PF = P + 5 * PSTRIDE;

  float u = PA[r * HID + h] + PC[(r - 1) * HID + h] + PE[(r + 1) * HID + h];
  float v = PB[r * HID + h] + PD[(r + 1) * HID + h] + PF[(r - 1) * HID + h];
  Uf[r * HID + h] = u;
  Vt[((h >> 2) * NN + r) * 4 + (h & 3)] = v;

  float u2 = u * u, v2 = v * v;
#pragma unroll
  for (int k = 32; k >= 1; k >>= 1) {
    u  += __shfl_xor(u,  k, 64);
    u2 += __shfl_xor(u2, k, 64);
    v  += __shfl_xor(v,  k, 64);
    v2 += __shfl_xor(v2, k, 64);
  }
  __shared__ float red[4][4];
  const int w = h >> 6;
  if ((h & 63) == 0) { red[w][0] = u; red[w][1] = u2; red[w][2] = v; red[w][3] = v2; }
  __syncthreads();
  if (h < 4)
    rowstat[h * NN + r] = red[0][h] + red[1][h] + red[2][h] + red[3][h];
}

// ---------------------------------------------------------------------------
// Kernel 3: pair epilogue with FUSED cross-dot. Interior: 2 rows x 256 j per
// block, 1024 threads = 256 j-slots x 4 h-quarters. Phase 1: each thread
// computes f32 partial dots U[i]·V[j] over its 64 h (V from L2, U from LDS);
// 4-way combine via LDS gives the exact cross term (replaces the bf16 MFMA
// cross kernel -> one launch + one gap + Cross buffer removed; absmax drops).
// Phase 2: the R4 main loop, reading V again (proven non-binding: R2==R4).
// ---------------------------------------------------------------------------
__global__ __launch_bounds__(1024, 8) void pair_kernel(
    const float* __restrict__ P,
    const float* __restrict__ Uf, const float* __restrict__ Vt,
    const float* __restrict__ rowstat,
    const float* __restrict__ gamma, const float* __restrict__ beta,
    const float* __restrict__ W2, const float* __restrict__ b2,
    float* __restrict__ out)
{
  const int wave = threadIdx.x >> 6, lane = threadIdx.x & 63;
  const float b2s = b2[0];

  if (blockIdx.x >= NB_BORDER) {
    const int bx = blockIdx.x - NB_BORDER;        // 0..509
    const int bi = bx >> 1;                       // 0..254
    const int i0 = 1 + (bi << 1);                 // 1,3,..,509
    const int i1 = i0 + 1;                        // 2,4,..,510
    const int tj = threadIdx.x & 255;             // j slot within half
    const int hq = threadIdx.x >> 8;              // 0..3: h-quarter
    const int jj = ((bx & 1) << 8) + tj;          // 0..511
    const int j  = jj < 1 ? 1 : (jj > 510 ? 510 : jj);

    __shared__ __align__(16) float Gs[HID], Bs[HID], Ws[HID], U0s[HID], U1s[HID];
    __shared__ float red[4][2][256];              // dot partials, then acc partials
    if (threadIdx.x < HID) {
      Gs[threadIdx.x]  = gamma[threadIdx.x];
      Bs[threadIdx.x]  = beta[threadIdx.x];
      Ws[threadIdx.x]  = W2[threadIdx.x];
      U0s[threadIdx.x] = Uf[i0 * HID + threadIdx.x];
      U1s[threadIdx.x] = Uf[i1 * HID + threadIdx.x];
    }
    __syncthreads();

    const float4* __restrict__ Vp  = (const float4*)Vt;   // [hb*NN + j]
    const float4* __restrict__ G4  = (const float4*)Gs;
    const float4* __restrict__ B4  = (const float4*)Bs;
    const float4* __restrict__ W4  = (const float4*)Ws;
    const float4* __restrict__ U04 = (const float4*)U0s;
    const float4* __restrict__ U14 = (const float4*)U1s;
    const int hb0 = hq << 4;                              // 0,16,32,48

    // ---- phase 1: f32 cross dots over this thread's 64 h ----------------
    float d0 = 0.f, d1 = 0.f;
#pragma unroll 4
    for (int hb = hb0; hb < hb0 + 16; hb++) {
      const float4 v4 = Vp[hb * NN + j];
      const float4 u0 = U04[hb];
      const float4 u1 = U14[hb];
      d0 = fmaf(v4.x, u0.x, fmaf(v4.y, u0.y, fmaf(v4.z, u0.z, fmaf(v4.w, u0.w, d0))));
      d1 = fmaf(v4.x, u1.x, fmaf(v4.y, u1.y, fmaf(v4.z, u1.z, fmaf(v4.w, u1.w, d1))));
    }
    red[hq][0][tj] = d0;
    red[hq][1][tj] = d1;
    __syncthreads();
    const float dot0 = (red[0][0][tj] + red[1][0][tj]) + (red[2][0][tj] + red[3][0][tj]);
    const float dot1 = (red[0][1][tj] + red[1][1][tj]) + (red[2][1][tj] + red[3][1][tj]);

    const float inv = 1.f / HID;
    const float sV  = rowstat[2 * NN + j], sV2 = rowstat[3 * NN + j];

    const float mu0 = (rowstat[0 * NN + i0] + sV) * inv;
    const float tq0 = fmaf(2.f, dot0, rowstat[1 * NN + i0] + sV2) * inv;
    const float rs0 = rsqrtf(tq0 - mu0 * mu0 + 1e-5f);
    const float mr0 = -mu0 * rs0;

    const float mu1 = (rowstat[0 * NN + i1] + sV) * inv;
    const float tq1 = fmaf(2.f, dot1, rowstat[1 * NN + i1] + sV2) * inv;
    const float rs1 = rsqrtf(tq1 - mu1 * mu1 + 1e-5f);
    const float mr1 = -mu1 * rs1;

    // ---- phase 2: main epilogue loop -------------------------------------
    float acc0 = 0.f, acc1 = 0.f;
#pragma unroll 4
    for (int hb = hb0; hb < hb0 + 16; hb++) {
      const float4 v4  = Vp[hb * NN + j];
      const float4 g   = G4[hb];
      const float4 be4 = B4[hb];
      const float4 w4  = W4[hb];
      const float4 u0  = U04[hb];
      const float4 u1  = U14[hb];
      {
        const float n0 = fmaf(fmaf(v4.x + u0.x, rs0, mr0), g.x, be4.x);
        acc0 = fmaf(celu1(n0), w4.x, acc0);
        const float n1 = fmaf(fmaf(v4.x + u1.x, rs1, mr1), g.x, be4.x);
        acc1 = fmaf(celu1(n1), w4.x, acc1);
      }
      {
        const float n0 = fmaf(fmaf(v4.y + u0.y, rs0, mr0), g.y, be4.y);
        acc0 = fmaf(celu1(n0), w4.y, acc0);
        const float n1 = fmaf(fmaf(v4.y + u1.y, rs1, mr1), g.y, be4.y);
        acc1 = fmaf(celu1(n1), w4.y, acc1);
      }
      {
        const float n0 = fmaf(fmaf(v4.z + u0.z, rs0, mr0), g.z, be4.z);
        acc0 = fmaf(celu1(n0), w4.z, acc0);
        const float n1 = fmaf(fmaf(v4.z + u1.z, rs1, mr1), g.z, be4.z);
        acc1 = fmaf(celu1(n1), w4.z, acc1);
      }
      {
        const float n0 = fmaf(fmaf(v4.w + u0.w, rs0, mr0), g.w, be4.w);
        acc0 = fmaf(celu1(n0), w4.w, acc0);
        const float n1 = fmaf(fmaf(v4.w + u1.w, rs1, mr1), g.w, be4.w);
        acc1 = fmaf(celu1(n1), w4.w, acc1);
      }
    }
    __syncthreads();                               // all dot-partial reads done
    if (hq > 0) { red[hq][0][tj] = acc0; red[hq][1][tj] = acc1; }
    __syncthreads();
    if (hq == 0 && jj >= 1 && jj <= 510) {
      out[i0 * NN + jj] =
          ((acc0 + red[1][0][tj]) + (red[2][0][tj] + red[3][0][tj])) + b2s;
      out[i1 * NN + jj] =
          ((acc1 + red[1][1][tj]) + (red[2][1][tj] + red[3][1][tj])) + b2s;
    }
  } else {
    // ---- border: 2044 pairs, 16 waves/block x 128 blocks -> 1 pair per wave
    const int gw = blockIdx.x * 16 + wave;             // 0..2047
    const float4* P4 = (const float4*)P;
    const float4* PA = P4 + 0 * (PSTRIDE / 4);
    const float4* PC = P4 + 1 * (PSTRIDE / 4);
    const float4* PE = P4 + 2 * (PSTRIDE / 4);
    const float4* PB = P4 + 3 * (PSTRIDE / 4);
    const float4* PD = P4 + 4 * (PSTRIDE / 4);
    const float4* PF = P4 + 5 * (PSTRIDE / 4);
    const float4 g  = ((const float4*)gamma)[lane];
    const float4 be = ((const float4*)beta)[lane];
    const float4 w2 = ((const float4*)W2)[lane];

    const int p = gw;
    if (p < 2044) {
      int i, j;
      if      (p < 512)  { i = 0;        j = p;        }
      else if (p < 1024) { i = 511;      j = p - 512;  }
      else if (p < 1534) { i = p - 1023; j = 0;        }
      else               { i = p - 1533; j = 511;      }

      const float4 a  = PA[i * H4 + lane];
      const float4 cu = PC[(i - 1) * H4 + lane];
      const float4 ed = PE[(i + 1) * H4 + lane];
      const float4 b  = PB[j * H4 + lane];
      const float4 du = PD[(j + 1) * H4 + lane];
      const float4 fd = PF[(j - 1) * H4 + lane];
      const float mu_m = (i >= 1 && j <= NN - 2) ? 1.f : 0.f;
      const float md_m = (i <= NN - 2 && j >= 1) ? 1.f : 0.f;

      float s0 = fmaf(md_m, ed.x + fd.x, fmaf(mu_m, cu.x + du.x, a.x + b.x));
      float s1 = fmaf(md_m, ed.y + fd.y, fmaf(mu_m, cu.y + du.y, a.y + b.y));
      float s2 = fmaf(md_m, ed.z + fd.z, fmaf(mu_m, cu.z + du.z, a.z + b.z));
      float s3 = fmaf(md_m, ed.w + fd.w, fmaf(mu_m, cu.w + du.w, a.w + b.w));

      float sum = (s0 + s1) + (s2 + s3);
      float ssq = fmaf(s0, s0, fmaf(s1, s1, fmaf(s2, s2, s3 * s3)));
#pragma unroll
      for (int off = 32; off >= 1; off >>= 1) {
        sum += __shfl_xor(sum, off, 64);
        ssq += __shfl_xor(ssq, off, 64);
      }
      const float mu  = sum * (1.f / HID);
      const float var = fmaf(ssq, 1.f / HID, -mu * mu);
      const float rs  = rsqrtf(var + 1e-5f);
      const float mrs = -mu * rs;

      auto nrm = [&](float s, float G, float Bt) {
        return fmaf(fmaf(s, rs, mrs), G, Bt);
      };
      float racc = fmaf(celu1(nrm(s0, g.x, be.x)), w2.x,
                   fmaf(celu1(nrm(s1, g.y, be.y)), w2.y,
                   fmaf(celu1(nrm(s2, g.z, be.z)), w2.z,
                        celu1(nrm(s3, g.w, be.w)) * w2.w)));
#pragma unroll
      for (int off = 32; off >= 1; off >>= 1)
        racc += __shfl_xor(racc, off, 64);
      if (lane == 0) out[i * NN + j] = racc + b2s;
    }
  }
}

extern "C" void kernel_launch(void* const* d_in, const int* in_sizes, int n_in,
                              void* d_out, int out_size, void* d_ws, size_t ws_size,
                              hipStream_t stream)
{
  const float* xl    = (const float*)d_in[0];
  const float* xr    = (const float*)d_in[1];
  const float* W1    = (const float*)d_in[2];
  const float* b1    = (const float*)d_in[3];
  const float* gamma = (const float*)d_in[4];
  const float* beta  = (const float*)d_in[5];
  const float* W2    = (const float*)d_in[6];
  const float* b2    = (const float*)d_in[7];
  float* out = (float*)d_out;

  float* P       = (float*)d_ws;                     // 3 MB
  float* Uf      = P + 6 * PSTRIDE;                  // 0.5 MB
  float* Vt      = Uf + NN * HID;                    // 0.5 MB (transposed V)
  float* rowstat = Vt + NN * HID;                    // 8 KB

  proj_kernel<<<dim3(NN / PROWS, 2), 256, 0, stream>>>(xl, xr, W1, b1, P);
  prep_kernel<<<NN, 256, 0, stream>>>(P, Uf, Vt, rowstat);
  pair_kernel<<<NB_BORDER + 510, 1024, 0, stream>>>(P, Uf, Vt, rowstat,
                                                    gamma, beta, W2, b2, out);
}